// Round 2
// baseline (305.071 us; speedup 1.0000x reference)
//
#include <hip/hip_runtime.h>
#include <math.h>

// Problem constants
#define NTOK 8192
#define MDIM 4096
#define NEXP 64
#define CAPACITY 128.0f

// Output layout (all fp32): [indices 8192][capacity 1][locations 8192][gates 8192][num_experts 1]
#define OFF_IDX  0
#define OFF_CAP  8192
#define OFF_LOC  8193
#define OFF_GATE 16385
#define OFF_NE   24577

// GEMM decomposition
#define NSLICE 4
#define KSLICE (MDIM / NSLICE)     // 1024 K per slice
#define KC     64                  // K-chunk per iteration
#define NCHUNK (KSLICE / KC)       // 16

// ws layout in 4-byte words: [cnt 8192][rk 8192][part NSLICE*8192*64][Wsplit 3*64*4096 bf16]
#define WS_CNT_OFF  0
#define WS_RK_OFF   8192
#define WS_PART_OFF 16384
#define WS_W_OFF    (WS_PART_OFF + NSLICE * NTOK * NEXP)

using bf16x8 = __attribute__((ext_vector_type(8))) short;
using f32x4  = __attribute__((ext_vector_type(4))) float;

// RNE float -> bf16 bits
static __device__ __forceinline__ unsigned short f2bf(float f) {
    union { float f; unsigned u; } v; v.f = f;
    unsigned r = v.u + 0x7fffu + ((v.u >> 16) & 1u);
    return (unsigned short)(r >> 16);
}
static __device__ __forceinline__ float bf2f(unsigned short h) {
    union { unsigned u; float f; } v; v.u = ((unsigned)h) << 16;
    return v.f;
}

// ---------------------------------------------------------------------------
// Pre-split W [64][4096] fp32 -> Ws[3][64][4096] bf16 (hi/mid/lo terms).
// ---------------------------------------------------------------------------
__global__ __launch_bounds__(256) void prep_w(
    const float* __restrict__ W, unsigned short* __restrict__ Ws)
{
    const int gid = blockIdx.x * 256 + threadIdx.x;   // 0..65535
    const int e   = gid >> 10;                        // expert row
    const int f4  = gid & 1023;                       // float4 within row
    float4 v = ((const float4*)W)[e * 1024 + f4];
    float av[4] = {v.x, v.y, v.z, v.w};
    unsigned short h[3][4];
    #pragma unroll
    for (int j = 0; j < 4; ++j) {
        float a = av[j];
        unsigned short b1 = f2bf(a);  float r1 = a  - bf2f(b1);
        unsigned short b2 = f2bf(r1); float r2 = r1 - bf2f(b2);
        unsigned short b3 = f2bf(r2);
        h[0][j] = b1; h[1][j] = b2; h[2][j] = b3;
    }
    #pragma unroll
    for (int t = 0; t < 3; ++t)
        *(ushort4*)&Ws[((size_t)(t * 64 + e)) * MDIM + f4 * 4] =
            make_ushort4(h[t][0], h[t][1], h[t][2], h[t][3]);
}

// ---------------------------------------------------------------------------
// Gate GEMM v2: no LDS, no barriers — fully independent waves.
// x has zero intra-block reuse (each element feeds exactly one wave's
// A-fragment), so LDS staging bought only coalescing at the price of a
// vmcnt(0)-draining barrier per chunk (the round-1 latency bind: 17.8K
// cy/chunk vs ~560 cy of work). Now each wave loads its A-fragments
// straight from global (2 float4/lane/k-step, 64B-segment coalescing),
// converts fp32 -> 3 bf16 planes in registers (same verified f2bf split,
// same 6-product MFMA order -> bitwise-identical accumulation), and keeps
// a 2-chunk-deep x prefetch in registers. Per chunk: W loads issued
// FIRST (ordered vmcnt: waiting on W leaves the newer x refill in
// flight), then both cvts (freeing the x buffer), then the x refill for
// c+2, then 48 MFMAs. Grid (128,4) = 512 blocks, 4 indep waves each.
// ---------------------------------------------------------------------------
__global__ __launch_bounds__(256, 2) void gate_mfma(
    const float* __restrict__ x,
    const unsigned short* __restrict__ Ws,
    float* __restrict__ part)
{
    const int tid   = threadIdx.x;
    const int lane  = tid & 63;
    const int wv    = tid >> 6;                // 0..3
    const int m     = lane & 15;               // token-in-group / expert row
    const int g     = lane >> 4;               // k-subgroup 0..3
    const int tok0  = blockIdx.x * 64;
    const int slice = blockIdx.y;
    const int k0    = slice * KSLICE;
    const int tok   = tok0 + wv * 16 + m;

    // per-lane base pointers (A-fragment layout: row m, k = g*8 + ...)
    const float* __restrict__ xp =
        x + (size_t)tok * MDIM + k0 + g * 8;
    const unsigned short* __restrict__ wp =
        Ws + (size_t)m * MDIM + k0 + g * 8;

    f32x4 acc[4];
    #pragma unroll
    for (int nt = 0; nt < 4; ++nt) acc[nt] = (f32x4){0.f, 0.f, 0.f, 0.f};

    // chunk c, lane covers ks0: [c*64 + g*8, +8) and ks1: [c*64+32+g*8, +8)
    auto loadx = [&](float4* d, int c) {
        const float* p = xp + c * KC;
        d[0] = *(const float4*)(p);
        d[1] = *(const float4*)(p + 4);
        d[2] = *(const float4*)(p + 32);
        d[3] = *(const float4*)(p + 36);
    };

    // 8 fp32 -> 3 bf16x8 planes (hi/mid/lo), RNE at each step
    auto cvt = [&](float4 lo, float4 hi, bf16x8& r0, bf16x8& r1, bf16x8& r2) {
        float f[8] = {lo.x, lo.y, lo.z, lo.w, hi.x, hi.y, hi.z, hi.w};
        #pragma unroll
        for (int j = 0; j < 8; ++j) {
            float a = f[j];
            unsigned short b1 = f2bf(a);  float t1 = a  - bf2f(b1);
            unsigned short b2 = f2bf(t1); float t2 = t1 - bf2f(b2);
            unsigned short b3 = f2bf(t2);
            r0[j] = (short)b1; r1[j] = (short)b2; r2[j] = (short)b3;
        }
    };

    // 24 MFMAs: 6 split-products (verified order), 4 nt-chains for ILP
    auto step = [&](const bf16x8* a, bf16x8 w[3][4]) {
        #pragma unroll
        for (int nt = 0; nt < 4; ++nt)
            acc[nt] = __builtin_amdgcn_mfma_f32_16x16x32_bf16(a[2], w[0][nt], acc[nt], 0, 0, 0);
        #pragma unroll
        for (int nt = 0; nt < 4; ++nt)
            acc[nt] = __builtin_amdgcn_mfma_f32_16x16x32_bf16(a[0], w[2][nt], acc[nt], 0, 0, 0);
        #pragma unroll
        for (int nt = 0; nt < 4; ++nt)
            acc[nt] = __builtin_amdgcn_mfma_f32_16x16x32_bf16(a[1], w[1][nt], acc[nt], 0, 0, 0);
        #pragma unroll
        for (int nt = 0; nt < 4; ++nt)
            acc[nt] = __builtin_amdgcn_mfma_f32_16x16x32_bf16(a[1], w[0][nt], acc[nt], 0, 0, 0);
        #pragma unroll
        for (int nt = 0; nt < 4; ++nt)
            acc[nt] = __builtin_amdgcn_mfma_f32_16x16x32_bf16(a[0], w[1][nt], acc[nt], 0, 0, 0);
        #pragma unroll
        for (int nt = 0; nt < 4; ++nt)
            acc[nt] = __builtin_amdgcn_mfma_f32_16x16x32_bf16(a[0], w[0][nt], acc[nt], 0, 0, 0);
    };

    // one chunk: issue W(c); cvt both ks (frees buf); refill buf with c+2;
    // MFMAs wait on W via counted vmcnt, leaving the refill in flight.
    auto body = [&](float4* buf, int c) {
        bf16x8 w0[3][4], w1[3][4];
        const unsigned short* q = wp + c * KC;
        #pragma unroll
        for (int t = 0; t < 3; ++t)
            #pragma unroll
            for (int nt = 0; nt < 4; ++nt) {
                const unsigned short* r = q + (size_t)(t * 64 + nt * 16) * MDIM;
                w0[t][nt] = *(const bf16x8*)(r);
                w1[t][nt] = *(const bf16x8*)(r + 32);
            }
        bf16x8 a0[3], a1[3];
        cvt(buf[0], buf[1], a0[0], a0[1], a0[2]);
        cvt(buf[2], buf[3], a1[0], a1[1], a1[2]);
        const int cn = (c + 2 < NCHUNK) ? c + 2 : NCHUNK - 1;  // clamped refill
        loadx(buf, cn);
        step(a0, w0);
        step(a1, w1);
    };

    float4 xa[4], xb[4];
    loadx(xa, 0);
    loadx(xb, 1);
    for (int cc = 0; cc < NCHUNK; cc += 2) {
        body(xa, cc);
        body(xb, cc + 1);
    }

    // C/D layout (m89-verified): col = lane&15, row = (lane>>4)*4 + reg.
    #pragma unroll
    for (int nt = 0; nt < 4; ++nt)
        #pragma unroll
        for (int r = 0; r < 4; ++r) {
            const int tokr = tok0 + wv * 16 + g * 4 + r;
            part[((size_t)slice * NTOK + tokr) * 64 + nt * 16 + m] = acc[nt][r];
        }
}

// ---------------------------------------------------------------------------
// Fused reduce + argmax/softmax + per-chunk histogram/rank. (unchanged)
// ---------------------------------------------------------------------------
template<int S>
__global__ __launch_bounds__(256) void reduce_count(
    const float* __restrict__ part,
    float* __restrict__ out,
    int* __restrict__ cnt,
    int* __restrict__ rk)
{
    __shared__ int eidx[64];

    const int tid  = threadIdx.x;
    const int lane = tid & 63;
    const int wv   = tid >> 6;
    const int tok0 = blockIdx.x * 64;
    const int trel = wv * 16 + (lane >> 2);
    const int tok  = tok0 + trel;
    const int q    = lane & 3;

    const float4* __restrict__ p4 = (const float4*)part;

    float4 a[4];
    #pragma unroll
    for (int r = 0; r < 4; ++r) a[r] = make_float4(0.f, 0.f, 0.f, 0.f);
    for (int s = 0; s < S; ++s) {
        #pragma unroll
        for (int r = 0; r < 4; ++r) {
            float4 v = p4[((size_t)s * NTOK + tok) * 16 + q * 4 + r];
            a[r].x += v.x; a[r].y += v.y; a[r].z += v.z; a[r].w += v.w;
        }
    }

    float vals[16];
    #pragma unroll
    for (int r = 0; r < 4; ++r) {
        vals[r * 4 + 0] = a[r].x; vals[r * 4 + 1] = a[r].y;
        vals[r * 4 + 2] = a[r].z; vals[r * 4 + 3] = a[r].w;
    }

    float bm = vals[0];
    int   be = q * 16;
    #pragma unroll
    for (int j = 1; j < 16; ++j)
        if (vals[j] > bm) { bm = vals[j]; be = q * 16 + j; }
    #pragma unroll
    for (int off = 1; off <= 2; off <<= 1) {
        float om = __shfl_xor(bm, off, 64);
        int   oe = __shfl_xor(be, off, 64);
        if (om > bm || (om == bm && oe < be)) { bm = om; be = oe; }
    }

    float es = 0.f;
    #pragma unroll
    for (int j = 0; j < 16; ++j) es += expf(vals[j] - bm);
    #pragma unroll
    for (int off = 1; off <= 2; off <<= 1)
        es += __shfl_xor(es, off, 64);

    if (q == 0) {
        out[OFF_IDX  + tok] = (float)be;
        out[OFF_GATE + tok] = 1.0f / es;
        eidx[trel] = be;
    }
    __syncthreads();

    if (tid < 64) {
        const int e = eidx[tid];
        const unsigned long long lt =
            (tid == 0) ? 0ull : ((~0ull) >> (64 - tid));
        unsigned long long mymask = 0;
        int myrk = 0;
        for (int ee = 0; ee < 64; ++ee) {
            unsigned long long mb = __ballot(e == ee);
            if (tid == ee) mymask = mb;
            if (e == ee)   myrk   = (int)__popcll(mb & lt);
        }
        cnt[blockIdx.x * 64 + tid] = (int)__popcll(mymask);
        rk[tok0 + tid] = myrk;
    }
    if (tid == 0 && blockIdx.x == 0) {
        out[OFF_CAP] = CAPACITY;
        out[OFF_NE]  = (float)NEXP;
    }
}

// ---------------------------------------------------------------------------
// Fused scan + final (unchanged): one block, 1024 threads.
// ---------------------------------------------------------------------------
__global__ __launch_bounds__(1024) void scan_final(
    const float* __restrict__ idxf,
    const int* __restrict__ cnt,
    const int* __restrict__ rk,
    float* __restrict__ out)
{
    __shared__ int lcnt[128 * 64];   // 32 KB
    __shared__ int wtot[16 * 64];    // 4 KB

    const int tid  = threadIdx.x;
    const int lane = tid & 63;
    const int w    = tid >> 6;       // 0..15

    #pragma unroll
    for (int j = 0; j < 8; ++j) lcnt[j * 1024 + tid] = cnt[j * 1024 + tid];
    __syncthreads();

    {
        int sum = 0;
        #pragma unroll
        for (int j = 0; j < 8; ++j) sum += lcnt[(w * 8 + j) * 64 + lane];
        wtot[w * 64 + lane] = sum;
    }
    __syncthreads();

    if (tid < 64) {
        int run = 0;
        #pragma unroll
        for (int w2 = 0; w2 < 16; ++w2) {
            int t = wtot[w2 * 64 + tid];
            wtot[w2 * 64 + tid] = run;
            run += t;
        }
    }
    __syncthreads();

    {
        int run = wtot[w * 64 + lane];
        #pragma unroll
        for (int j = 0; j < 8; ++j) {
            int c = w * 8 + j;
            int v = lcnt[c * 64 + lane];
            lcnt[c * 64 + lane] = run;
            run += v;
        }
    }
    __syncthreads();

    #pragma unroll
    for (int j = 0; j < 8; ++j) {
        int s = j * 1024 + tid;
        int e = (int)idxf[s];
        out[OFF_LOC + s] = (float)(lcnt[(s >> 6) * 64 + e] + rk[s]);
    }
}

extern "C" void kernel_launch(void* const* d_in, const int* in_sizes, int n_in,
                              void* d_out, int out_size, void* d_ws, size_t ws_size,
                              hipStream_t stream)
{
    const float* x = (const float*)d_in[0];   // [8192, 4096] fp32
    const float* W = (const float*)d_in[1];   // [64, 4096] fp32
    float* out = (float*)d_out;               // 24578 fp32

    int*   cnt  = (int*)d_ws + WS_CNT_OFF;
    int*   rk   = (int*)d_ws + WS_RK_OFF;
    float* part = (float*)d_ws + WS_PART_OFF;
    unsigned short* Ws = (unsigned short*)((int*)d_ws + WS_W_OFF);

    prep_w<<<256, 256, 0, stream>>>(W, Ws);
    gate_mfma<<<dim3(128, NSLICE), 256, 0, stream>>>(x, Ws, part);
    reduce_count<NSLICE><<<128, 256, 0, stream>>>(part, out, cnt, rk);
    scan_final<<<1, 1024, 0, stream>>>(out + OFF_IDX, cnt, rk, out);
}

// Round 3
// 273.414 us; speedup vs baseline: 1.1158x; 1.1158x over previous
//
#include <hip/hip_runtime.h>
#include <math.h>

// Problem constants
#define NTOK 8192
#define MDIM 4096
#define NEXP 64
#define CAPACITY 128.0f

// Output layout (all fp32): [indices 8192][capacity 1][locations 8192][gates 8192][num_experts 1]
#define OFF_IDX  0
#define OFF_CAP  8192
#define OFF_LOC  8193
#define OFF_GATE 16385
#define OFF_NE   24577

#define KC 64                      // K-chunk per iteration

// ws layout in 4-byte words: [cnt 8192][rk 8192][Ws 3*64*4096 bf16 = 393216 w][part S*8192*64]
#define WS_CNT_OFF  0
#define WS_RK_OFF   8192
#define WS_W_OFF    16384
#define WS_PART_OFF (16384 + (3 * NEXP * MDIM) / 2)   // 409600

using bf16x8 = __attribute__((ext_vector_type(8))) short;
using f32x4  = __attribute__((ext_vector_type(4))) float;

// RNE float -> bf16 bits
static __device__ __forceinline__ unsigned short f2bf(float f) {
    union { float f; unsigned u; } v; v.f = f;
    unsigned r = v.u + 0x7fffu + ((v.u >> 16) & 1u);
    return (unsigned short)(r >> 16);
}
static __device__ __forceinline__ float bf2f(unsigned short h) {
    union { unsigned u; float f; } v; v.u = ((unsigned)h) << 16;
    return v.f;
}

// ---------------------------------------------------------------------------
// Pre-split W [64][4096] fp32 -> Ws[3][64][4096] bf16 (hi/mid/lo terms).
// ---------------------------------------------------------------------------
__global__ __launch_bounds__(256) void prep_w(
    const float* __restrict__ W, unsigned short* __restrict__ Ws)
{
    const int gid = blockIdx.x * 256 + threadIdx.x;   // 0..65535
    const int e   = gid >> 10;                        // expert row
    const int f4  = gid & 1023;                       // float4 within row
    float4 v = ((const float4*)W)[e * 1024 + f4];
    float av[4] = {v.x, v.y, v.z, v.w};
    unsigned short h[3][4];
    #pragma unroll
    for (int j = 0; j < 4; ++j) {
        float a = av[j];
        unsigned short b1 = f2bf(a);  float r1 = a  - bf2f(b1);
        unsigned short b2 = f2bf(r1); float r2 = r1 - bf2f(b2);
        unsigned short b3 = f2bf(r2);
        h[0][j] = b1; h[1][j] = b2; h[2][j] = b3;
    }
    #pragma unroll
    for (int t = 0; t < 3; ++t)
        *(ushort4*)&Ws[((size_t)(t * 64 + e)) * MDIM + f4 * 4] =
            make_ushort4(h[t][0], h[t][1], h[t][2], h[t][3]);
}

// ---------------------------------------------------------------------------
// Gate GEMM v3: wave-private LDS x-staging via global_load_lds, ZERO
// barriers, XOR-swizzled rows, direct L2-hot W loads.
//  - Round-1 lesson: s_barrier forces vmcnt(0) drain -> no pipelining.
//  - Round-2 lesson: per-lane scattered x + compiler refusing to hoist
//    24 W loads (VGPR_Count=84) -> serial L2 latency, 2 waves/SIMD TLP.
//  - Here: each wave DMAs its own 16 tok x 64 K fp32 chunk (4 KB) into its
//    private LDS region (4 x global_load_lds width-16, coalesced 256B/row,
//    source pre-swizzled per T21), reads it back with swizzled
//    ds_read_b128 (T2: phys_slot = logical ^ (tok&7), kills the 256B-row
//    16-way conflict), cvts fp32 -> 3 bf16 planes in-reg (identical f2bf
//    split + 6-product MFMA order -> per-slice chain bitwise-preserved).
//  - No __syncthreads anywhere: only within-wave waitcnt ordering.
//  - Grid (128, S=8) = 1024 blocks; launch_bounds(256,3) -> VGPR cap 170
//    so the 24 W frags CAN stay live; ~12 waves/CU.
// ---------------------------------------------------------------------------
template<int S>
__global__ __launch_bounds__(256, 3) void gate_mfma(
    const float* __restrict__ x,
    const unsigned short* __restrict__ Ws,
    float* __restrict__ part)
{
    constexpr int KSL = MDIM / S;       // K per slice
    constexpr int NCH = KSL / KC;       // chunks per slice

    // [buf][wave][tok_local 16][f4 slot 16], slots XOR-swizzled by (tok&7)
    __shared__ __align__(16) float4 xs[2][4][16][16];   // 32 KB

    const int tid   = threadIdx.x;
    const int lane  = tid & 63;
    const int wv    = tid >> 6;                // 0..3
    const int m     = lane & 15;               // token-in-group / expert row
    const int g     = lane >> 4;               // k-subgroup 0..3
    const int tok0  = blockIdx.x * 64;
    const int slice = blockIdx.y;
    const int k0    = slice * KSL;             // float offset

    const float4* __restrict__ x4 = (const float4*)x;
    const unsigned short* __restrict__ wp =
        Ws + (size_t)m * MDIM + k0 + g * 8;

    // ---- wave-private async stage of chunk c into xs[b][wv] ------------
    // inst j stages tokens j*4..j*4+3: lane l -> token j*4+(l>>4),
    // phys slot (l&15); source = logical slot (l&15)^(tok&7) (inverse swz).
    auto stage = [&](int c, int b) {
        #pragma unroll
        for (int j = 0; j < 4; ++j) {
            const int tl  = j * 4 + (lane >> 4);
            const int src = (lane & 15) ^ (tl & 7);
            const float4* gsrc = x4 + (size_t)(tok0 + wv * 16 + tl) * (MDIM / 4)
                                 + (k0 >> 2) + c * 16 + src;
            void* ldst = (void*)&xs[b][wv][j * 4][0];   // +lane*16 by HW
            __builtin_amdgcn_global_load_lds(
                (const __attribute__((address_space(1))) void*)gsrc,
                (__attribute__((address_space(3))) void*)ldst, 16, 0, 0);
        }
    };

    // ---- swizzled read of my 8 floats for k-half ks ---------------------
    auto readx = [&](int b, int ks, float4& lo, float4& hi) {
        const int l0 = ks * 8 + g * 2;          // logical f4 slot
        lo = xs[b][wv][m][(l0    ) ^ (m & 7)];
        hi = xs[b][wv][m][(l0 + 1) ^ (m & 7)];
    };

    // 8 fp32 -> 3 bf16x8 planes (hi/mid/lo), RNE at each step
    auto cvt = [&](float4 lo, float4 hi, bf16x8& r0, bf16x8& r1, bf16x8& r2) {
        float f[8] = {lo.x, lo.y, lo.z, lo.w, hi.x, hi.y, hi.z, hi.w};
        #pragma unroll
        for (int j = 0; j < 8; ++j) {
            float a = f[j];
            unsigned short b1 = f2bf(a);  float t1 = a  - bf2f(b1);
            unsigned short b2 = f2bf(t1); float t2 = t1 - bf2f(b2);
            unsigned short b3 = f2bf(t2);
            r0[j] = (short)b1; r1[j] = (short)b2; r2[j] = (short)b3;
        }
    };

    f32x4 acc[4];
    #pragma unroll
    for (int nt = 0; nt < 4; ++nt) acc[nt] = (f32x4){0.f, 0.f, 0.f, 0.f};

    // 24 MFMAs: 6 split-products (verified order), 4 nt-chains for ILP
    auto step = [&](const bf16x8* a, bf16x8 w[3][4]) {
        #pragma unroll
        for (int nt = 0; nt < 4; ++nt)
            acc[nt] = __builtin_amdgcn_mfma_f32_16x16x32_bf16(a[2], w[0][nt], acc[nt], 0, 0, 0);
        #pragma unroll
        for (int nt = 0; nt < 4; ++nt)
            acc[nt] = __builtin_amdgcn_mfma_f32_16x16x32_bf16(a[0], w[2][nt], acc[nt], 0, 0, 0);
        #pragma unroll
        for (int nt = 0; nt < 4; ++nt)
            acc[nt] = __builtin_amdgcn_mfma_f32_16x16x32_bf16(a[1], w[1][nt], acc[nt], 0, 0, 0);
        #pragma unroll
        for (int nt = 0; nt < 4; ++nt)
            acc[nt] = __builtin_amdgcn_mfma_f32_16x16x32_bf16(a[1], w[0][nt], acc[nt], 0, 0, 0);
        #pragma unroll
        for (int nt = 0; nt < 4; ++nt)
            acc[nt] = __builtin_amdgcn_mfma_f32_16x16x32_bf16(a[0], w[1][nt], acc[nt], 0, 0, 0);
        #pragma unroll
        for (int nt = 0; nt < 4; ++nt)
            acc[nt] = __builtin_amdgcn_mfma_f32_16x16x32_bf16(a[0], w[0][nt], acc[nt], 0, 0, 0);
    };

    stage(0, 0);

    for (int c = 0; c < NCH; ++c) {
        const int cur = c & 1;
        if (c + 1 < NCH) stage(c + 1, cur ^ 1);   // deep prefetch in flight

        // W chunk (L2-hot): ks0 batch first; ks1 issued before step0 so its
        // latency hides under the first MFMA cluster.
        bf16x8 w0[3][4], w1[3][4];
        const unsigned short* q = wp + c * KC;
        #pragma unroll
        for (int t = 0; t < 3; ++t)
            #pragma unroll
            for (int nt = 0; nt < 4; ++nt)
                w0[t][nt] = *(const bf16x8*)(q + (size_t)(t * 64 + nt * 16) * MDIM);

        float4 lo0, hi0, lo1, hi1;
        readx(cur, 0, lo0, hi0);      // waits stage(c) via counted vmcnt
        readx(cur, 1, lo1, hi1);
        bf16x8 a0[3], a1[3];
        cvt(lo0, hi0, a0[0], a0[1], a0[2]);
        cvt(lo1, hi1, a1[0], a1[1], a1[2]);

        #pragma unroll
        for (int t = 0; t < 3; ++t)
            #pragma unroll
            for (int nt = 0; nt < 4; ++nt)
                w1[t][nt] = *(const bf16x8*)(q + (size_t)(t * 64 + nt * 16) * MDIM + 32);

        step(a0, w0);
        step(a1, w1);
    }

    // C/D layout (m89-verified): col = lane&15, row = (lane>>4)*4 + reg.
    #pragma unroll
    for (int nt = 0; nt < 4; ++nt)
        #pragma unroll
        for (int r = 0; r < 4; ++r) {
            const int tokr = tok0 + wv * 16 + g * 4 + r;
            part[((size_t)slice * NTOK + tokr) * 64 + nt * 16 + m] = acc[nt][r];
        }
}

// ---------------------------------------------------------------------------
// Fused reduce + argmax/softmax + per-chunk histogram/rank. (unchanged)
// ---------------------------------------------------------------------------
template<int S>
__global__ __launch_bounds__(256) void reduce_count(
    const float* __restrict__ part,
    float* __restrict__ out,
    int* __restrict__ cnt,
    int* __restrict__ rk)
{
    __shared__ int eidx[64];

    const int tid  = threadIdx.x;
    const int lane = tid & 63;
    const int wv   = tid >> 6;
    const int tok0 = blockIdx.x * 64;
    const int trel = wv * 16 + (lane >> 2);
    const int tok  = tok0 + trel;
    const int q    = lane & 3;

    const float4* __restrict__ p4 = (const float4*)part;

    float4 a[4];
    #pragma unroll
    for (int r = 0; r < 4; ++r) a[r] = make_float4(0.f, 0.f, 0.f, 0.f);
    for (int s = 0; s < S; ++s) {
        #pragma unroll
        for (int r = 0; r < 4; ++r) {
            float4 v = p4[((size_t)s * NTOK + tok) * 16 + q * 4 + r];
            a[r].x += v.x; a[r].y += v.y; a[r].z += v.z; a[r].w += v.w;
        }
    }

    float vals[16];
    #pragma unroll
    for (int r = 0; r < 4; ++r) {
        vals[r * 4 + 0] = a[r].x; vals[r * 4 + 1] = a[r].y;
        vals[r * 4 + 2] = a[r].z; vals[r * 4 + 3] = a[r].w;
    }

    float bm = vals[0];
    int   be = q * 16;
    #pragma unroll
    for (int j = 1; j < 16; ++j)
        if (vals[j] > bm) { bm = vals[j]; be = q * 16 + j; }
    #pragma unroll
    for (int off = 1; off <= 2; off <<= 1) {
        float om = __shfl_xor(bm, off, 64);
        int   oe = __shfl_xor(be, off, 64);
        if (om > bm || (om == bm && oe < be)) { bm = om; be = oe; }
    }

    float es = 0.f;
    #pragma unroll
    for (int j = 0; j < 16; ++j) es += expf(vals[j] - bm);
    #pragma unroll
    for (int off = 1; off <= 2; off <<= 1)
        es += __shfl_xor(es, off, 64);

    if (q == 0) {
        out[OFF_IDX  + tok] = (float)be;
        out[OFF_GATE + tok] = 1.0f / es;
        eidx[trel] = be;
    }
    __syncthreads();

    if (tid < 64) {
        const int e = eidx[tid];
        const unsigned long long lt =
            (tid == 0) ? 0ull : ((~0ull) >> (64 - tid));
        unsigned long long mymask = 0;
        int myrk = 0;
        for (int ee = 0; ee < 64; ++ee) {
            unsigned long long mb = __ballot(e == ee);
            if (tid == ee) mymask = mb;
            if (e == ee)   myrk   = (int)__popcll(mb & lt);
        }
        cnt[blockIdx.x * 64 + tid] = (int)__popcll(mymask);
        rk[tok0 + tid] = myrk;
    }
    if (tid == 0 && blockIdx.x == 0) {
        out[OFF_CAP] = CAPACITY;
        out[OFF_NE]  = (float)NEXP;
    }
}

// ---------------------------------------------------------------------------
// Fused scan + final (unchanged): one block, 1024 threads.
// ---------------------------------------------------------------------------
__global__ __launch_bounds__(1024) void scan_final(
    const float* __restrict__ idxf,
    const int* __restrict__ cnt,
    const int* __restrict__ rk,
    float* __restrict__ out)
{
    __shared__ int lcnt[128 * 64];   // 32 KB
    __shared__ int wtot[16 * 64];    // 4 KB

    const int tid  = threadIdx.x;
    const int lane = tid & 63;
    const int w    = tid >> 6;       // 0..15

    #pragma unroll
    for (int j = 0; j < 8; ++j) lcnt[j * 1024 + tid] = cnt[j * 1024 + tid];
    __syncthreads();

    {
        int sum = 0;
        #pragma unroll
        for (int j = 0; j < 8; ++j) sum += lcnt[(w * 8 + j) * 64 + lane];
        wtot[w * 64 + lane] = sum;
    }
    __syncthreads();

    if (tid < 64) {
        int run = 0;
        #pragma unroll
        for (int w2 = 0; w2 < 16; ++w2) {
            int t = wtot[w2 * 64 + tid];
            wtot[w2 * 64 + tid] = run;
            run += t;
        }
    }
    __syncthreads();

    {
        int run = wtot[w * 64 + lane];
        #pragma unroll
        for (int j = 0; j < 8; ++j) {
            int c = w * 8 + j;
            int v = lcnt[c * 64 + lane];
            lcnt[c * 64 + lane] = run;
            run += v;
        }
    }
    __syncthreads();

    #pragma unroll
    for (int j = 0; j < 8; ++j) {
        int s = j * 1024 + tid;
        int e = (int)idxf[s];
        out[OFF_LOC + s] = (float)(lcnt[(s >> 6) * 64 + e] + rk[s]);
    }
}

extern "C" void kernel_launch(void* const* d_in, const int* in_sizes, int n_in,
                              void* d_out, int out_size, void* d_ws, size_t ws_size,
                              hipStream_t stream)
{
    const float* x = (const float*)d_in[0];   // [8192, 4096] fp32
    const float* W = (const float*)d_in[1];   // [64, 4096] fp32
    float* out = (float*)d_out;               // 24578 fp32

    int*   cnt  = (int*)d_ws + WS_CNT_OFF;
    int*   rk   = (int*)d_ws + WS_RK_OFF;
    unsigned short* Ws = (unsigned short*)((int*)d_ws + WS_W_OFF);
    float* part = (float*)d_ws + WS_PART_OFF;

    prep_w<<<256, 256, 0, stream>>>(W, Ws);

    const size_t base = (size_t)WS_PART_OFF * 4;
    const size_t per_slice = (size_t)NTOK * 64 * 4;   // 2 MB

    if (ws_size >= base + 8 * per_slice) {
        gate_mfma<8><<<dim3(128, 8), 256, 0, stream>>>(x, Ws, part);
        reduce_count<8><<<128, 256, 0, stream>>>(part, out, cnt, rk);
    } else if (ws_size >= base + 4 * per_slice) {
        gate_mfma<4><<<dim3(128, 4), 256, 0, stream>>>(x, Ws, part);
        reduce_count<4><<<128, 256, 0, stream>>>(part, out, cnt, rk);
    } else if (ws_size >= base + 2 * per_slice) {
        gate_mfma<2><<<dim3(128, 2), 256, 0, stream>>>(x, Ws, part);
        reduce_count<2><<<128, 256, 0, stream>>>(part, out, cnt, rk);
    } else {
        gate_mfma<1><<<dim3(128, 1), 256, 0, stream>>>(x, Ws, part);
        reduce_count<1><<<128, 256, 0, stream>>>(part, out, cnt, rk);
    }

    scan_final<<<1, 1024, 0, stream>>>(out + OFF_IDX, cnt, rk, out);
}

// Round 5
// 260.139 us; speedup vs baseline: 1.1727x; 1.0510x over previous
//
#include <hip/hip_runtime.h>
#include <math.h>

// Problem constants
#define NTOK 8192
#define MDIM 4096
#define NEXP 64
#define CAPACITY 128.0f

// Output layout (all fp32): [indices 8192][capacity 1][locations 8192][gates 8192][num_experts 1]
#define OFF_IDX  0
#define OFF_CAP  8192
#define OFF_LOC  8193
#define OFF_GATE 16385
#define OFF_NE   24577

#define KC 32                      // K-chunk per iteration (floats)

// 32-token chunks for histogram/rank/scan: 8192/32 = 256 chunks
#define NCHK 256

// ws layout in 4-byte words:
//   [cnt 256*64=16384][rk 8192][sbase 16384][Ws 3*64*4096 bf16 = 393216 w][part S*8192*64]
#define WS_CNT_OFF  0
#define WS_RK_OFF   16384
#define WS_SB_OFF   24576
#define WS_W_OFF    40960
#define WS_PART_OFF (40960 + (3 * NEXP * MDIM) / 2)   // 434176 words

using bf16x8 = __attribute__((ext_vector_type(8))) short;
using f32x4  = __attribute__((ext_vector_type(4))) float;

// RNE float -> bf16 bits
static __device__ __forceinline__ unsigned short f2bf(float f) {
    union { float f; unsigned u; } v; v.f = f;
    unsigned r = v.u + 0x7fffu + ((v.u >> 16) & 1u);
    return (unsigned short)(r >> 16);
}
static __device__ __forceinline__ float bf2f(unsigned short h) {
    union { unsigned u; float f; } v; v.u = ((unsigned)h) << 16;
    return v.f;
}

// ---------------------------------------------------------------------------
// Pre-split W [64][4096] fp32 -> Ws[3][64][4096] bf16 (hi/mid/lo terms).
// ---------------------------------------------------------------------------
__global__ __launch_bounds__(256) void prep_w(
    const float* __restrict__ W, unsigned short* __restrict__ Ws)
{
    const int gid = blockIdx.x * 256 + threadIdx.x;   // 0..65535
    const int e   = gid >> 10;                        // expert row
    const int f4  = gid & 1023;                       // float4 within row
    float4 v = ((const float4*)W)[e * 1024 + f4];
    float av[4] = {v.x, v.y, v.z, v.w};
    unsigned short h[3][4];
    #pragma unroll
    for (int j = 0; j < 4; ++j) {
        float a = av[j];
        unsigned short b1 = f2bf(a);  float r1 = a  - bf2f(b1);
        unsigned short b2 = f2bf(r1); float r2 = r1 - bf2f(b2);
        unsigned short b3 = f2bf(r2);
        h[0][j] = b1; h[1][j] = b2; h[2][j] = b3;
    }
    #pragma unroll
    for (int t = 0; t < 3; ++t)
        *(ushort4*)&Ws[((size_t)(t * 64 + e)) * MDIM + f4 * 4] =
            make_ushort4(h[t][0], h[t][1], h[t][2], h[t][3]);
}

// ---------------------------------------------------------------------------
// Gate GEMM v4 (resubmit after infra failure): 1-wave blocks, 32 tokens/wave
// (M_rep=2 -> W reuse x2), KC=32, wave-private 8KB LDS double-buffer, no
// barriers, W issued BEFORE the x-prefetch DMA (FIFO vmcnt: waiting on W
// leaves the stage in flight).
//  - Round-3 lessons: occupancy 27% / ~2 blocks-CU resident was the cap
//    (S=4 at 158us vs S=8 at 122us proves TLP sensitivity); and
//    stage-before-W meant every W wait drained the prefetch.
//  - Grid (256 token-groups, S slices); S=16 -> 4096 independent waves.
//  - Per chunk: 12 W-frag loads (L1/L2-hot, shared by both A-tiles),
//    4 DMA stage insts for next chunk, 4 swizzled ds_read_b128, 2 in-reg
//    fp32->3xbf16 cvts, 48 MFMAs (6 split-products x 2 groups x 4 nt).
//  - Numerics: identical f2bf split + same 6-product chain order.
// ---------------------------------------------------------------------------
template<int S>
__global__ __launch_bounds__(64, 3) void gate_mfma(
    const float* __restrict__ x,
    const unsigned short* __restrict__ Ws,
    float* __restrict__ part)
{
    constexpr int KSL = MDIM / S;       // K per slice
    constexpr int NCH = KSL / KC;       // chunks per slice

    // [buf][token row 0..31][f4 slot 0..7], slot XOR-swizzled by (row&7)
    __shared__ __align__(16) float4 xs[2][32][8];   // 8 KB

    const int lane  = threadIdx.x & 63;
    const int m     = lane & 15;               // token-in-tile / expert row
    const int g     = lane >> 4;               // k-subgroup 0..3
    const int tok0  = blockIdx.x * 32;
    const int slice = blockIdx.y;
    const int k0    = slice * KSL;             // float offset

    const float4* __restrict__ x4 = (const float4*)x;
    const unsigned short* __restrict__ wp =
        Ws + (size_t)m * MDIM + k0 + g * 8;

    // ---- wave-private async stage of chunk c into xs[b] ----------------
    // inst j: lane l -> row j*8 + (l>>3), phys slot (l&7); source slot =
    // (l&7) ^ (row&7)  (inverse of the read-side swizzle).
    auto stage = [&](int c, int b) {
        #pragma unroll
        for (int j = 0; j < 4; ++j) {
            const int row  = j * 8 + (lane >> 3);
            const int srcs = (lane & 7) ^ (row & 7);
            const float4* gsrc = x4 + (size_t)(tok0 + row) * (MDIM / 4)
                                 + (k0 >> 2) + c * 8 + srcs;
            void* ldst = (void*)&xs[b][j * 8][0];   // +lane*16 by HW
            __builtin_amdgcn_global_load_lds(
                (const __attribute__((address_space(1))) void*)gsrc,
                (__attribute__((address_space(3))) void*)ldst, 16, 0, 0);
        }
    };

    // 8 fp32 -> 3 bf16x8 planes (hi/mid/lo), RNE at each step
    auto cvt = [&](float4 lo, float4 hi, bf16x8& r0, bf16x8& r1, bf16x8& r2) {
        float f[8] = {lo.x, lo.y, lo.z, lo.w, hi.x, hi.y, hi.z, hi.w};
        #pragma unroll
        for (int j = 0; j < 8; ++j) {
            float a = f[j];
            unsigned short b1 = f2bf(a);  float t1 = a  - bf2f(b1);
            unsigned short b2 = f2bf(t1); float t2 = t1 - bf2f(b2);
            unsigned short b3 = f2bf(t2);
            r0[j] = (short)b1; r1[j] = (short)b2; r2[j] = (short)b3;
        }
    };

    f32x4 acc[2][4];
    #pragma unroll
    for (int gr = 0; gr < 2; ++gr)
        #pragma unroll
        for (int nt = 0; nt < 4; ++nt) acc[gr][nt] = (f32x4){0.f, 0.f, 0.f, 0.f};

    stage(0, 0);

    for (int c = 0; c < NCH; ++c) {
        const int cur = c & 1;

        // W frags FIRST (oldest in vm queue): waiting on them later keeps
        // the newer stage(c+1) DMA in flight across the MFMA cluster.
        bf16x8 w[3][4];
        const unsigned short* q = wp + c * KC;
        #pragma unroll
        for (int t = 0; t < 3; ++t)
            #pragma unroll
            for (int nt = 0; nt < 4; ++nt)
                w[t][nt] = *(const bf16x8*)(q + (size_t)(t * 64 + nt * 16) * MDIM);

        if (c + 1 < NCH) stage(c + 1, cur ^ 1);

        // A-tiles: group gr -> rows gr*16 + m; swizzled slot pair (2g, 2g+1)
        bf16x8 a[2][3];
        #pragma unroll
        for (int gr = 0; gr < 2; ++gr) {
            const int row = gr * 16 + m;
            float4 lo = xs[cur][row][(2 * g    ) ^ (m & 7)];
            float4 hi = xs[cur][row][(2 * g + 1) ^ (m & 7)];
            cvt(lo, hi, a[gr][0], a[gr][1], a[gr][2]);
        }

        // 6 split-products (verified order), 2 groups x 4 nt chains
        #pragma unroll
        for (int gr = 0; gr < 2; ++gr)
            #pragma unroll
            for (int nt = 0; nt < 4; ++nt)
                acc[gr][nt] = __builtin_amdgcn_mfma_f32_16x16x32_bf16(a[gr][2], w[0][nt], acc[gr][nt], 0, 0, 0);
        #pragma unroll
        for (int gr = 0; gr < 2; ++gr)
            #pragma unroll
            for (int nt = 0; nt < 4; ++nt)
                acc[gr][nt] = __builtin_amdgcn_mfma_f32_16x16x32_bf16(a[gr][0], w[2][nt], acc[gr][nt], 0, 0, 0);
        #pragma unroll
        for (int gr = 0; gr < 2; ++gr)
            #pragma unroll
            for (int nt = 0; nt < 4; ++nt)
                acc[gr][nt] = __builtin_amdgcn_mfma_f32_16x16x32_bf16(a[gr][1], w[1][nt], acc[gr][nt], 0, 0, 0);
        #pragma unroll
        for (int gr = 0; gr < 2; ++gr)
            #pragma unroll
            for (int nt = 0; nt < 4; ++nt)
                acc[gr][nt] = __builtin_amdgcn_mfma_f32_16x16x32_bf16(a[gr][1], w[0][nt], acc[gr][nt], 0, 0, 0);
        #pragma unroll
        for (int gr = 0; gr < 2; ++gr)
            #pragma unroll
            for (int nt = 0; nt < 4; ++nt)
                acc[gr][nt] = __builtin_amdgcn_mfma_f32_16x16x32_bf16(a[gr][0], w[1][nt], acc[gr][nt], 0, 0, 0);
        #pragma unroll
        for (int gr = 0; gr < 2; ++gr)
            #pragma unroll
            for (int nt = 0; nt < 4; ++nt)
                acc[gr][nt] = __builtin_amdgcn_mfma_f32_16x16x32_bf16(a[gr][0], w[0][nt], acc[gr][nt], 0, 0, 0);
    }

    // C/D layout (m89-verified): col = lane&15 (expert nt*16+m),
    // row = (lane>>4)*4 + r (token within 16-tile).
    #pragma unroll
    for (int gr = 0; gr < 2; ++gr)
        #pragma unroll
        for (int nt = 0; nt < 4; ++nt)
            #pragma unroll
            for (int r = 0; r < 4; ++r) {
                const int tokr = tok0 + gr * 16 + g * 4 + r;
                part[((size_t)slice * NTOK + tokr) * 64 + nt * 16 + m] = acc[gr][nt][r];
            }
}

// ---------------------------------------------------------------------------
// Fused reduce + argmax/softmax + per-32-token-chunk histogram/rank.
// 256 blocks (full GPU) x 256 thr; 32 tokens/block, 8 lanes per token
// (8 experts each). Deterministic ascending-s sums per (token,expert).
// ---------------------------------------------------------------------------
template<int S>
__global__ __launch_bounds__(256) void reduce_count(
    const float* __restrict__ part,
    float* __restrict__ out,
    int* __restrict__ cnt,
    int* __restrict__ rk)
{
    __shared__ int eidx[32];

    const int tid  = threadIdx.x;
    const int tok0 = blockIdx.x * 32;
    const int trel = tid >> 3;          // 0..31
    const int tok  = tok0 + trel;
    const int q    = tid & 7;           // expert octet

    const float4* __restrict__ p4 = (const float4*)part;

    float4 a[2];
    #pragma unroll
    for (int r = 0; r < 2; ++r) a[r] = make_float4(0.f, 0.f, 0.f, 0.f);
    for (int s = 0; s < S; ++s) {
        #pragma unroll
        for (int r = 0; r < 2; ++r) {
            float4 v = p4[((size_t)s * NTOK + tok) * 16 + q * 2 + r];
            a[r].x += v.x; a[r].y += v.y; a[r].z += v.z; a[r].w += v.w;
        }
    }

    float vals[8] = {a[0].x, a[0].y, a[0].z, a[0].w,
                     a[1].x, a[1].y, a[1].z, a[1].w};

    float bm = vals[0];
    int   be = q * 8;
    #pragma unroll
    for (int j = 1; j < 8; ++j)
        if (vals[j] > bm) { bm = vals[j]; be = q * 8 + j; }
    #pragma unroll
    for (int off = 1; off <= 4; off <<= 1) {
        float om = __shfl_xor(bm, off, 64);
        int   oe = __shfl_xor(be, off, 64);
        if (om > bm || (om == bm && oe < be)) { bm = om; be = oe; }
    }

    float es = 0.f;
    #pragma unroll
    for (int j = 0; j < 8; ++j) es += expf(vals[j] - bm);
    #pragma unroll
    for (int off = 1; off <= 4; off <<= 1)
        es += __shfl_xor(es, off, 64);

    if (q == 0) {
        out[OFF_IDX  + tok] = (float)be;
        out[OFF_GATE + tok] = 1.0f / es;
        eidx[trel] = be;
    }
    __syncthreads();

    if (tid < 64) {  // wave 0: histogram of the 32 tokens over 64 experts
        const int e = (tid < 32) ? eidx[tid] : -1;
        const unsigned long long lt =
            (tid == 0) ? 0ull : ((~0ull) >> (64 - tid));
        unsigned long long mymask = 0;
        int myrk = 0;
        for (int ee = 0; ee < 64; ++ee) {
            unsigned long long mb = __ballot(e == ee);
            if (tid == ee) mymask = mb;          // tid = expert id
            if (e == ee)   myrk   = (int)__popcll(mb & lt);
        }
        cnt[blockIdx.x * 64 + tid] = (int)__popcll(mymask);
        if (tid < 32) rk[tok0 + tid] = myrk;
    }
    if (tid == 0 && blockIdx.x == 0) {
        out[OFF_CAP] = CAPACITY;
        out[OFF_NE]  = (float)NEXP;
    }
}

// ---------------------------------------------------------------------------
// Per-expert exclusive scan over the 256 chunk counts. 64 blocks (one per
// expert) x 64 lanes; pure shuffle, no LDS.
// ---------------------------------------------------------------------------
__global__ __launch_bounds__(64) void scan_e(
    const int* __restrict__ cnt, int* __restrict__ sb)
{
    const int e = blockIdx.x;
    const int l = threadIdx.x & 63;

    int v[4], s[4];
    #pragma unroll
    for (int seg = 0; seg < 4; ++seg)
        v[seg] = cnt[(seg * 64 + l) * 64 + e];

    #pragma unroll
    for (int seg = 0; seg < 4; ++seg) {
        int sv = v[seg];
        #pragma unroll
        for (int off = 1; off <= 32; off <<= 1) {
            int u = __shfl_up(sv, off, 64);
            if (l >= off) sv += u;
        }
        s[seg] = sv;
    }
    int t0 = __shfl(s[0], 63, 64);
    int t1 = __shfl(s[1], 63, 64);
    int t2 = __shfl(s[2], 63, 64);
    s[1] += t0; s[2] += t0 + t1; s[3] += t0 + t1 + t2;

    #pragma unroll
    for (int seg = 0; seg < 4; ++seg)
        sb[(seg * 64 + l) * 64 + e] = s[seg] - v[seg];   // exclusive
}

// ---------------------------------------------------------------------------
// Parallel location emit: loc[s] = sbase[chunk(s)][idx[s]] + rk[s].
// ---------------------------------------------------------------------------
__global__ __launch_bounds__(256) void emit_loc(
    const float* __restrict__ idxf,
    const int* __restrict__ sb,
    const int* __restrict__ rk,
    float* __restrict__ out)
{
    const int s = blockIdx.x * 256 + threadIdx.x;
    const int e = (int)idxf[s];
    out[OFF_LOC + s] = (float)(sb[(s >> 5) * 64 + e] + rk[s]);
}

extern "C" void kernel_launch(void* const* d_in, const int* in_sizes, int n_in,
                              void* d_out, int out_size, void* d_ws, size_t ws_size,
                              hipStream_t stream)
{
    const float* x = (const float*)d_in[0];   // [8192, 4096] fp32
    const float* W = (const float*)d_in[1];   // [64, 4096] fp32
    float* out = (float*)d_out;               // 24578 fp32

    int*   cnt  = (int*)d_ws + WS_CNT_OFF;
    int*   rk   = (int*)d_ws + WS_RK_OFF;
    int*   sb   = (int*)d_ws + WS_SB_OFF;
    unsigned short* Ws = (unsigned short*)((int*)d_ws + WS_W_OFF);
    float* part = (float*)d_ws + WS_PART_OFF;

    prep_w<<<256, 256, 0, stream>>>(W, Ws);

    const size_t base = (size_t)WS_PART_OFF * 4;
    const size_t per_slice = (size_t)NTOK * 64 * 4;   // 2 MB

    if (ws_size >= base + 16 * per_slice) {
        gate_mfma<16><<<dim3(256, 16), 64, 0, stream>>>(x, Ws, part);
        reduce_count<16><<<256, 256, 0, stream>>>(part, out, cnt, rk);
    } else if (ws_size >= base + 8 * per_slice) {
        gate_mfma<8><<<dim3(256, 8), 64, 0, stream>>>(x, Ws, part);
        reduce_count<8><<<256, 256, 0, stream>>>(part, out, cnt, rk);
    } else if (ws_size >= base + 4 * per_slice) {
        gate_mfma<4><<<dim3(256, 4), 64, 0, stream>>>(x, Ws, part);
        reduce_count<4><<<256, 256, 0, stream>>>(part, out, cnt, rk);
    } else if (ws_size >= base + 2 * per_slice) {
        gate_mfma<2><<<dim3(256, 2), 64, 0, stream>>>(x, Ws, part);
        reduce_count<2><<<256, 256, 0, stream>>>(part, out, cnt, rk);
    } else {
        gate_mfma<1><<<dim3(256, 1), 64, 0, stream>>>(x, Ws, part);
        reduce_count<1><<<256, 256, 0, stream>>>(part, out, cnt, rk);
    }

    scan_e<<<64, 64, 0, stream>>>(cnt, sb);
    emit_loc<<<32, 256, 0, stream>>>(out + OFF_IDX, sb, rk, out);
}

// Round 6
// 227.759 us; speedup vs baseline: 1.3394x; 1.1422x over previous
//
#include <hip/hip_runtime.h>
#include <math.h>

// Problem constants
#define NTOK 8192
#define MDIM 4096
#define NEXP 64
#define CAPACITY 128.0f

// Output layout (all fp32): [indices 8192][capacity 1][locations 8192][gates 8192][num_experts 1]
#define OFF_IDX  0
#define OFF_CAP  8192
#define OFF_LOC  8193
#define OFF_GATE 16385
#define OFF_NE   24577

#define NSLICE 16                  // K-slices; W-slice = 3*64*256*2B = 96 KB LDS
#define KSL    (MDIM / NSLICE)     // 256 floats per slice
#define KC     32                  // K-chunk per MFMA step
#define NCH    (KSL / KC)          // 8 chunks

// ws layout in 4-byte words: [cnt 256*64][rk 8192][part 16*8192*64]
#define WS_CNT_OFF  0
#define WS_RK_OFF   16384
#define WS_PART_OFF 24576

using bf16x8 = __attribute__((ext_vector_type(8))) short;
using f32x4  = __attribute__((ext_vector_type(4))) float;

// RNE float -> bf16 bits
static __device__ __forceinline__ unsigned short f2bf(float f) {
    union { float f; unsigned u; } v; v.f = f;
    unsigned r = v.u + 0x7fffu + ((v.u >> 16) & 1u);
    return (unsigned short)(r >> 16);
}
static __device__ __forceinline__ float bf2f(unsigned short h) {
    union { unsigned u; float f; } v; v.u = ((unsigned)h) << 16;
    return v.f;
}

// ---------------------------------------------------------------------------
// Gate GEMM v5: persistent W-slice in LDS.
//  - Rounds 1/2/3/5 post-mortem: with W loaded from global inside the loop,
//    the compiler (VGPR_Count=68 every round) serializes the 12-fragment W
//    batch against its MFMAs -> each chunk is a serial L2 latency chain, and
//    W shares the vmcnt FIFO with the x-prefetch DMA so W waits drain it.
//  - Here: each block stages its ENTIRE (slice, 3-plane) W into LDS once
//    (raw fp32 read + in-kernel split -> also deletes the prep_w kernel),
//    then the 8-chunk loop reads W via swizzled ds_read_b128 (lgkmcnt
//    domain, ~120cy). The ONLY vmcnt traffic in the loop is the wave's
//    private 4-inst x DMA -> clean counted waits, no entanglement.
//  - 512 thr = 8 waves (2/SIMD), LDS 96K W + 8x4K x = 128 KB, ONE barrier.
//  - W LDS swizzle: phys_slot = log_slot ^ ((e>>1)&3) -> B-frag read is
//    2-way (free). x swizzle as in v4/v5 (verified).
//  - Numerics: identical f2bf split, 6-product order, K-partition -> logits
//    bitwise-identical to round 5.
// ---------------------------------------------------------------------------
__global__ __launch_bounds__(512, 2) void gate_mfma(
    const float* __restrict__ x,
    const float* __restrict__ W,
    float* __restrict__ part)
{
    // [c*3+t][expert][32 bf16], 16B slots XOR-swizzled by ((e>>1)&3)
    __shared__ __align__(16) unsigned short wl[NCH * 3][64][32];  // 96 KB
    // per-wave x chunk: [wave][token row 0..31][f4 slot 0..7], row-swizzled
    __shared__ __align__(16) float4 xs[8][32][8];                 // 32 KB

    const int tid   = threadIdx.x;
    const int lane  = tid & 63;
    const int wv    = tid >> 6;                // 0..7
    const int m     = lane & 15;
    const int g     = lane >> 4;               // 0..3
    const int tok0  = blockIdx.x * 256 + wv * 32;
    const int slice = blockIdx.y;
    const int k0    = slice * KSL;

    const float4* __restrict__ x4 = (const float4*)x;

    // ---- wave-private async x stage of chunk c into xs[wv] -------------
    auto stage = [&](int c) {
        #pragma unroll
        for (int j = 0; j < 4; ++j) {
            const int row  = j * 8 + (lane >> 3);
            const int srcs = (lane & 7) ^ (row & 7);
            const float4* gsrc = x4 + (size_t)(tok0 + row) * (MDIM / 4)
                                 + (k0 >> 2) + c * 8 + srcs;
            void* ldst = (void*)&xs[wv][j * 8][0];   // +lane*16 by HW
            __builtin_amdgcn_global_load_lds(
                (const __attribute__((address_space(1))) void*)gsrc,
                (__attribute__((address_space(3))) void*)ldst, 16, 0, 0);
        }
    };

    stage(0);   // x(0) DMA overlaps the W split below; drained at barrier

    // ---- one-time W-slice split: 64KB fp32 -> 3 bf16 planes in LDS -----
    #pragma unroll
    for (int r = 0; r < 8; ++r) {
        const int j4  = r * 512 + tid;          // float4 idx in [64][64]
        const int e   = j4 >> 6;
        const int kk4 = j4 & 63;
        float4 v = *(const float4*)(W + (size_t)e * MDIM + k0 + kk4 * 4);
        const int c    = kk4 >> 3;
        const int slog = (kk4 >> 1) & 3;        // logical 16B slot
        const int half = kk4 & 1;
        const int phys = slog ^ ((e >> 1) & 3);
        float av[4] = {v.x, v.y, v.z, v.w};
        unsigned short h[3][4];
        #pragma unroll
        for (int j = 0; j < 4; ++j) {
            float a = av[j];
            unsigned short b1 = f2bf(a);  float t1 = a  - bf2f(b1);
            unsigned short b2 = f2bf(t1); float t2 = t1 - bf2f(b2);
            unsigned short b3 = f2bf(t2);
            h[0][j] = b1; h[1][j] = b2; h[2][j] = b3;
        }
        #pragma unroll
        for (int t = 0; t < 3; ++t)
            *(ushort4*)&wl[c * 3 + t][e][phys * 8 + half * 4] =
                make_ushort4(h[t][0], h[t][1], h[t][2], h[t][3]);
    }
    __syncthreads();   // W ready for all waves; x(0) DMA drained too

    // 8 fp32 -> 3 bf16x8 planes (hi/mid/lo), RNE at each step
    auto cvt = [&](float4 lo, float4 hi, bf16x8& r0, bf16x8& r1, bf16x8& r2) {
        float f[8] = {lo.x, lo.y, lo.z, lo.w, hi.x, hi.y, hi.z, hi.w};
        #pragma unroll
        for (int j = 0; j < 8; ++j) {
            float a = f[j];
            unsigned short b1 = f2bf(a);  float t1 = a  - bf2f(b1);
            unsigned short b2 = f2bf(t1); float t2 = t1 - bf2f(b2);
            unsigned short b3 = f2bf(t2);
            r0[j] = (short)b1; r1[j] = (short)b2; r2[j] = (short)b3;
        }
    };

    f32x4 acc[2][4];
    #pragma unroll
    for (int gr = 0; gr < 2; ++gr)
        #pragma unroll
        for (int nt = 0; nt < 4; ++nt) acc[gr][nt] = (f32x4){0.f, 0.f, 0.f, 0.f};

    for (int c = 0; c < NCH; ++c) {
        // W frags from LDS (lgkmcnt domain; swizzled, 2-way = free)
        bf16x8 w[3][4];
        #pragma unroll
        for (int t = 0; t < 3; ++t)
            #pragma unroll
            for (int nt = 0; nt < 4; ++nt) {
                const int e    = nt * 16 + m;
                const int phys = g ^ ((e >> 1) & 3);
                w[t][nt] = *(const bf16x8*)&wl[c * 3 + t][e][phys * 8];
            }

        // x frags (vmcnt wait covers only this wave's 4 DMAs)
        bf16x8 a[2][3];
        #pragma unroll
        for (int gr = 0; gr < 2; ++gr) {
            const int row = gr * 16 + m;
            float4 lo = xs[wv][row][(2 * g    ) ^ (m & 7)];
            float4 hi = xs[wv][row][(2 * g + 1) ^ (m & 7)];
            cvt(lo, hi, a[gr][0], a[gr][1], a[gr][2]);
        }

        // x regs extracted (lgkm drained by cvt) -> safe to overwrite buffer
        __builtin_amdgcn_sched_barrier(0);
        if (c + 1 < NCH) stage(c + 1);   // HBM latency hides under MFMAs

        // 6 split-products (verified order), 2 groups x 4 nt chains
        #pragma unroll
        for (int gr = 0; gr < 2; ++gr)
            #pragma unroll
            for (int nt = 0; nt < 4; ++nt)
                acc[gr][nt] = __builtin_amdgcn_mfma_f32_16x16x32_bf16(a[gr][2], w[0][nt], acc[gr][nt], 0, 0, 0);
        #pragma unroll
        for (int gr = 0; gr < 2; ++gr)
            #pragma unroll
            for (int nt = 0; nt < 4; ++nt)
                acc[gr][nt] = __builtin_amdgcn_mfma_f32_16x16x32_bf16(a[gr][0], w[2][nt], acc[gr][nt], 0, 0, 0);
        #pragma unroll
        for (int gr = 0; gr < 2; ++gr)
            #pragma unroll
            for (int nt = 0; nt < 4; ++nt)
                acc[gr][nt] = __builtin_amdgcn_mfma_f32_16x16x32_bf16(a[gr][1], w[1][nt], acc[gr][nt], 0, 0, 0);
        #pragma unroll
        for (int gr = 0; gr < 2; ++gr)
            #pragma unroll
            for (int nt = 0; nt < 4; ++nt)
                acc[gr][nt] = __builtin_amdgcn_mfma_f32_16x16x32_bf16(a[gr][1], w[0][nt], acc[gr][nt], 0, 0, 0);
        #pragma unroll
        for (int gr = 0; gr < 2; ++gr)
            #pragma unroll
            for (int nt = 0; nt < 4; ++nt)
                acc[gr][nt] = __builtin_amdgcn_mfma_f32_16x16x32_bf16(a[gr][0], w[1][nt], acc[gr][nt], 0, 0, 0);
        #pragma unroll
        for (int gr = 0; gr < 2; ++gr)
            #pragma unroll
            for (int nt = 0; nt < 4; ++nt)
                acc[gr][nt] = __builtin_amdgcn_mfma_f32_16x16x32_bf16(a[gr][0], w[0][nt], acc[gr][nt], 0, 0, 0);
    }

    // C/D layout (m89-verified): col = lane&15, row = (lane>>4)*4 + reg.
    #pragma unroll
    for (int gr = 0; gr < 2; ++gr)
        #pragma unroll
        for (int nt = 0; nt < 4; ++nt)
            #pragma unroll
            for (int r = 0; r < 4; ++r) {
                const int tokr = tok0 + gr * 16 + g * 4 + r;
                part[((size_t)slice * NTOK + tokr) * 64 + nt * 16 + m] = acc[gr][nt][r];
            }
}

// ---------------------------------------------------------------------------
// Fused reduce + argmax/softmax + per-32-token-chunk histogram/rank.
// 256 blocks x 256 thr; 32 tokens/block, 8 lanes per token. (unchanged)
// ---------------------------------------------------------------------------
template<int S>
__global__ __launch_bounds__(256) void reduce_count(
    const float* __restrict__ part,
    float* __restrict__ out,
    int* __restrict__ cnt,
    int* __restrict__ rk)
{
    __shared__ int eidx[32];

    const int tid  = threadIdx.x;
    const int tok0 = blockIdx.x * 32;
    const int trel = tid >> 3;          // 0..31
    const int tok  = tok0 + trel;
    const int q    = tid & 7;           // expert octet

    const float4* __restrict__ p4 = (const float4*)part;

    float4 a[2];
    #pragma unroll
    for (int r = 0; r < 2; ++r) a[r] = make_float4(0.f, 0.f, 0.f, 0.f);
    for (int s = 0; s < S; ++s) {
        #pragma unroll
        for (int r = 0; r < 2; ++r) {
            float4 v = p4[((size_t)s * NTOK + tok) * 16 + q * 2 + r];
            a[r].x += v.x; a[r].y += v.y; a[r].z += v.z; a[r].w += v.w;
        }
    }

    float vals[8] = {a[0].x, a[0].y, a[0].z, a[0].w,
                     a[1].x, a[1].y, a[1].z, a[1].w};

    float bm = vals[0];
    int   be = q * 8;
    #pragma unroll
    for (int j = 1; j < 8; ++j)
        if (vals[j] > bm) { bm = vals[j]; be = q * 8 + j; }
    #pragma unroll
    for (int off = 1; off <= 4; off <<= 1) {
        float om = __shfl_xor(bm, off, 64);
        int   oe = __shfl_xor(be, off, 64);
        if (om > bm || (om == bm && oe < be)) { bm = om; be = oe; }
    }

    float es = 0.f;
    #pragma unroll
    for (int j = 0; j < 8; ++j) es += expf(vals[j] - bm);
    #pragma unroll
    for (int off = 1; off <= 4; off <<= 1)
        es += __shfl_xor(es, off, 64);

    if (q == 0) {
        out[OFF_IDX  + tok] = (float)be;
        out[OFF_GATE + tok] = 1.0f / es;
        eidx[trel] = be;
    }
    __syncthreads();

    if (tid < 64) {  // wave 0: histogram of the 32 tokens over 64 experts
        const int e = (tid < 32) ? eidx[tid] : -1;
        const unsigned long long lt =
            (tid == 0) ? 0ull : ((~0ull) >> (64 - tid));
        unsigned long long mymask = 0;
        int myrk = 0;
        for (int ee = 0; ee < 64; ++ee) {
            unsigned long long mb = __ballot(e == ee);
            if (tid == ee) mymask = mb;          // tid = expert id
            if (e == ee)   myrk   = (int)__popcll(mb & lt);
        }
        cnt[blockIdx.x * 64 + tid] = (int)__popcll(mymask);
        if (tid < 32) rk[tok0 + tid] = myrk;
    }
    if (tid == 0 && blockIdx.x == 0) {
        out[OFF_CAP] = CAPACITY;
        out[OFF_NE]  = (float)NEXP;
    }
}

// ---------------------------------------------------------------------------
// Fused scan + emit, ONE block x 512 thr (replaces scan_e + emit_loc).
// Per-expert exclusive scan over 256 chunk counts (8 segments/expert),
// then parallel location emit from LDS bases.
// ---------------------------------------------------------------------------
__global__ __launch_bounds__(512) void scan_emit(
    const float* __restrict__ idxf,
    const int* __restrict__ cnt,
    const int* __restrict__ rk,
    float* __restrict__ out)
{
    __shared__ int sc[256][64];   // 64 KB, [chunk][e] -> becomes excl. base
    __shared__ int ps[64][8];     // per-(expert, segment) totals

    const int tid = threadIdx.x;
    const int e   = tid >> 3;     // 0..63
    const int q   = tid & 7;      // segment 0..7 (32 chunks each)

    #pragma unroll
    for (int r = 0; r < 32; ++r) sc[0][r * 512 + tid] = cnt[r * 512 + tid];
    __syncthreads();

    {   // segment totals
        int sum = 0;
        #pragma unroll
        for (int j = 0; j < 32; ++j) sum += sc[q * 32 + j][e];
        ps[e][q] = sum;
    }
    __syncthreads();

    {   // exclusive base across segments, then in-place chunk scan
        int base = 0;
        for (int qq = 0; qq < 8; ++qq) { if (qq < q) base += ps[e][qq]; }
        #pragma unroll
        for (int j = 0; j < 32; ++j) {
            int ch = q * 32 + j;
            int v  = sc[ch][e];
            sc[ch][e] = base;
            base += v;
        }
    }
    __syncthreads();

    #pragma unroll
    for (int r = 0; r < 16; ++r) {
        const int s  = r * 512 + tid;
        const int ee = (int)idxf[s];
        out[OFF_LOC + s] = (float)(sc[s >> 5][ee] + rk[s]);
    }
}

extern "C" void kernel_launch(void* const* d_in, const int* in_sizes, int n_in,
                              void* d_out, int out_size, void* d_ws, size_t ws_size,
                              hipStream_t stream)
{
    const float* x = (const float*)d_in[0];   // [8192, 4096] fp32
    const float* W = (const float*)d_in[1];   // [64, 4096] fp32
    float* out = (float*)d_out;               // 24578 fp32

    int*   cnt  = (int*)d_ws + WS_CNT_OFF;
    int*   rk   = (int*)d_ws + WS_RK_OFF;
    float* part = (float*)d_ws + WS_PART_OFF;
    // ws need: (24576 + 16*8192*64) * 4B ~ 33.7 MB (round-5 run proved
    // ws_size >= 35 MB on this problem instance)

    gate_mfma<<<dim3(32, NSLICE), 512, 0, stream>>>(x, W, part);
    reduce_count<NSLICE><<<256, 256, 0, stream>>>(part, out, cnt, rk);
    scan_emit<<<1, 512, 0, stream>>>(out + OFF_IDX, cnt, rk, out);
}